// Round 7
// baseline (145.348 us; speedup 1.0000x reference)
//
#include <hip/hip_runtime.h>
#include <hip/hip_fp16.h>

#define T1 512
#define NB 32      // batches
#define NP 96      // 3 pairs * 32 batches
#define DHEAD 64

#define RSLOTS 152                 // LDS ring slots (1 KB column each) = 155648 B
#define RBYTES (RSLOTS * 1024)
#define PFD 20                     // producer prefetch distance (columns ahead)

typedef __attribute__((ext_vector_type(8))) short bf16x8;
typedef __attribute__((ext_vector_type(4))) float f32x4;
typedef __attribute__((ext_vector_type(4))) unsigned int u32x4;

// ---------------- kernel 1: row-normalize x,y -> bf16 ----------------
__global__ __launch_bounds__(256) void k_normalize(const float* __restrict__ x,
                                                   const float* __restrict__ y,
                                                   ushort* __restrict__ xb,
                                                   ushort* __restrict__ yb) {
  int wid  = threadIdx.x >> 6;
  int lane = threadIdx.x & 63;
  int row  = blockIdx.x * 4 + wid;          // 0 .. 32767
  const float* src; ushort* dst;
  if (row < NB * T1) { src = x + (size_t)row * DHEAD;            dst = xb + (size_t)row * DHEAD; }
  else { int r2 = row - NB * T1; src = y + (size_t)r2 * DHEAD;   dst = yb + (size_t)r2 * DHEAD; }
  float v = src[lane];
  float s = v * v;
  #pragma unroll
  for (int off = 32; off > 0; off >>= 1) s += __shfl_xor(s, off);
  float rn = 1.0f / fmaxf(sqrtf(s), 1e-12f);
  float o = v * rn;
  unsigned u = __float_as_uint(o);
  unsigned r = (u + 0x7fffu + ((u >> 16) & 1u)) >> 16;   // RNE to bf16
  dst[lane] = (ushort)r;
}

// ---------------- kernel 2: MFMA bf16 GEMM -> W[p][b][j][i] = exp(-(1-dot)) f16 ----------------
// 256 thr = 4 waves (2x2), tile 128x128, wave tile 64x64. K=64 = 2 mfma k-steps.
// Fragments loaded directly from global (xb/yb K-contiguous, L2-resident).
__global__ __launch_bounds__(256) void k_gemm_w(const ushort* __restrict__ xb,
                                                const ushort* __restrict__ yb,
                                                __half* __restrict__ W) {
  int pb = blockIdx.z;            // 0..95
  int p  = pb >> 5;               // 0:xy 1:xx 2:yy
  int b  = pb & 31;
  const ushort* A  = ((p == 2) ? yb : xb) + (size_t)b * T1 * DHEAD;  // i-side (M)
  const ushort* Bm = ((p == 1) ? xb : yb) + (size_t)b * T1 * DHEAD;  // j-side (N)

  int wid = threadIdx.x >> 6, lane = threadIdx.x & 63;
  int wm = wid >> 1, wn = wid & 1;
  int i0 = blockIdx.x * 128 + wm * 64;
  int j0 = blockIdx.y * 128 + wn * 64;
  int lr = lane & 15, kg = lane >> 4;

  f32x4 acc[4][4];
  #pragma unroll
  for (int ic = 0; ic < 4; ++ic)
    #pragma unroll
    for (int jc = 0; jc < 4; ++jc) acc[ic][jc] = (f32x4){0.f, 0.f, 0.f, 0.f};

  #pragma unroll
  for (int kk = 0; kk < 2; ++kk) {
    int ko = kk * 32 + kg * 8;
    bf16x8 af[4], bf[4];
    #pragma unroll
    for (int ic = 0; ic < 4; ++ic)
      af[ic] = *reinterpret_cast<const bf16x8*>(A + (size_t)(i0 + ic * 16 + lr) * DHEAD + ko);
    #pragma unroll
    for (int jc = 0; jc < 4; ++jc)
      bf[jc] = *reinterpret_cast<const bf16x8*>(Bm + (size_t)(j0 + jc * 16 + lr) * DHEAD + ko);
    #pragma unroll
    for (int ic = 0; ic < 4; ++ic)
      #pragma unroll
      for (int jc = 0; jc < 4; ++jc)
        acc[ic][jc] = __builtin_amdgcn_mfma_f32_16x16x32_bf16(af[ic], bf[jc], acc[ic][jc], 0, 0, 0);
  }

  // epilogue: D col = lane&15 -> j, row = (lane>>4)*4 + r -> i; pack 4 i's as 8B store
  const float NLOG2E = -1.44269504088896340736f;
  __half* Wp = W + (size_t)pb * (T1 * T1);
  int ib = kg << 2;
  #pragma unroll
  for (int ic = 0; ic < 4; ++ic) {
    int i = i0 + ic * 16 + ib;
    #pragma unroll
    for (int jc = 0; jc < 4; ++jc) {
      int j = j0 + jc * 16 + lr;
      union { __half h[4]; uint2 u; } pk;
      #pragma unroll
      for (int r = 0; r < 4; ++r) {
        float d = 1.0f - acc[ic][jc][r];
        pk.h[r] = __float2half(exp2f(NLOG2E * d));
      }
      *reinterpret_cast<uint2*>(Wp + (size_t)j * T1 + i) = pk.u;
    }
  }
}

// ---------------- kernel 3: soft-DTW, exp domain, skew-2, LDS column ring ----------------
// DP math identical to the absmax-0.0 round-4 version. New W feed path:
//  - W column c (1 KB) DMA'd to LDS slot c%152 via global_load_lds_dwordx4:
//    coalesced 16B/lane global reads, wave-uniform LDS base + lane*16 (HW semantics).
//  - producer runs PFD=20 columns ahead; ONE counted `s_waitcnt vmcnt(10)` per 8-step
//    group (loads stay in flight across groups — T4 pattern). No VGPR window at all.
//  - consumer ds_read_b128 2 steps ahead (static d0/d1/d2 rotation), compiler lgkmcnt.
// Margins: col c issued at step c-20, earliest land ~c-18 > last read of col c-152 at
// c-26 (write-after-read safe); group-top vmcnt(10) guarantees cols <= tb+9 landed,
// covering the k+2 read-ahead (max col tb+9).
__global__ __launch_bounds__(64, 1) void k_dtw(const __half* __restrict__ W,
                                               float* __restrict__ res) {
  __shared__ __attribute__((aligned(16))) char ring[RBYTES];
  int prob = blockIdx.x;
  const __half* Wp = W + (size_t)prob * (T1 * T1);
  int lane = threadIdx.x;

  float V[8];
  #pragma unroll
  for (int r = 0; r < 8; ++r) V[r] = 0.f;
  float B2 = 0.f;                          // base, log2 units (integer-valued, exact)
  float V7d0 = 0.f, V7d1 = 0.f;            // V[7] delay line (capture at step top)
  float B2d0 = 0.f, B2d1 = 0.f;            // matching bases

  // producer: DMA column c into its ring slot (uniform slot base; per-lane global addr)
  auto issueLoad = [&](int c) {
    int cc = c > T1 - 1 ? T1 - 1 : c;                 // clamp keeps vmcnt cadence uniform
    const __half* gp = Wp + ((size_t)cc << 9) + (lane << 3);
    char* lp = &ring[(cc % RSLOTS) << 10];            // wave-uniform (cc uniform)
    __builtin_amdgcn_global_load_lds(
        (const __attribute__((address_space(1))) void*)gp,
        (__attribute__((address_space(3))) void*)lp, 16, 0, 0);
  };

  // consumer: my 16B slice of the column for step t (col j = clamp(t - 2*lane))
  auto readSlot = [&](int t) -> u32x4 {
    int j = t - 2 * lane;
    j = j < 0 ? 0 : (j > T1 - 1 ? T1 - 1 : j);
    int slot = j % RSLOTS;                            // per-lane, VALU magic-mul
    return *reinterpret_cast<const u32x4*>(&ring[(slot << 10) + (lane << 4)]);
  };

  auto step = [&](int t, u32x4 raw, bool renorm) {
    // read neighbor delayed pairs (state as of end of step t-1), then shift my line
    float nbUp  = __shfl_up(V7d0, 1);   // neighbor col j   (up)
    float nbUpB = __shfl_up(B2d0, 1);
    float nbDg  = __shfl_up(V7d1, 1);   // neighbor col j-1 (diag)
    float nbDgB = __shfl_up(B2d1, 1);
    V7d1 = V7d0; V7d0 = V[7];
    B2d1 = B2d0; B2d0 = B2;
    if (lane == 0) {                    // DP row 0 boundary: E=0 except E[0][0]=1
      nbUp = 0.f; nbUpB = B2;
      nbDg = (t == 0) ? 1.f : 0.f; nbDgB = B2;
    }
    int du = (int)(B2 - nbUpB); du = du > 160 ? 160 : (du < -160 ? -160 : du);
    int dd = (int)(B2 - nbDgB); dd = dd > 160 ? 160 : (dd < -160 ? -160 : dd);
    float up = ldexpf(nbUp, du);        // exact base conversion (power of 2)
    float dg = ldexpf(nbDg, dd);

    union { u32x4 u; __half h[8]; } cv; cv.u = raw;
    float wv[8];
    #pragma unroll
    for (int r = 0; r < 8; ++r) wv[r] = __half2float(cv.h[r]);

    int j = t - 2 * lane;
    bool active = ((unsigned)j < (unsigned)T1);
    if (active) {
      float c = fmaf(wv[0], up, wv[0] * (dg + V[0]));
      float Vn[8]; Vn[0] = c;
      #pragma unroll
      for (int r = 1; r < 8; ++r) {
        c = fmaf(wv[r], c, wv[r] * (V[r-1] + V[r]));
        Vn[r] = c;
      }
      if (renorm) {
        float m = fmaxf(fmaxf(fmaxf(Vn[0], Vn[1]), fmaxf(Vn[2], Vn[3])),
                        fmaxf(fmaxf(Vn[4], Vn[5]), fmaxf(Vn[6], Vn[7])));
        int e = (int)((__float_as_uint(m) >> 23) & 0xFF) - 127;
        e = e < -126 ? -126 : (e > 126 ? 126 : e);
        float sc = __uint_as_float((unsigned)(127 - e) << 23);  // 2^(-e), exact
        #pragma unroll
        for (int r = 0; r < 8; ++r) V[r] = Vn[r] * sc;
        B2 -= (float)e;
      } else {
        #pragma unroll
        for (int r = 0; r < 8; ++r) V[r] = Vn[r];
      }
    }
  };

  // producer prologue: columns 0..19 in flight
  #pragma unroll
  for (int c = 0; c < PFD; ++c) issueLoad(c);
  // consumer prologue: steps 0,1 data (cols <= 1 landed after vmcnt(PFD-2))
  asm volatile("s_waitcnt vmcnt(18)" ::: "memory");
  u32x4 d0 = readSlot(0);
  u32x4 d1 = readSlot(1);

  for (int tb = 0; tb < 640; tb += 8) {     // lane63 last active col at t=637
    asm volatile("s_waitcnt vmcnt(10)" ::: "memory");  // cols <= tb+9 landed
    #pragma unroll
    for (int k = 0; k < 8; ++k) {
      u32x4 d2 = readSlot(tb + k + 2);      // LDS read 2 steps ahead
      step(tb + k, d0, (k == 7));
      issueLoad(tb + k + PFD);              // keep 20 columns in flight
      d0 = d1; d1 = d2;
    }
  }

  if (lane == 63) {
    res[prob] = (B2 - log2f(V[7])) * 0.69314718055994530942f;
  }
}

// ---------------- kernel 4: combine ----------------
__global__ void k_combine(const float* __restrict__ res, float* __restrict__ out) {
  int b = threadIdx.x;
  if (b < NB) out[b] = res[b] - 0.5f * (res[NB + b] + res[2 * NB + b]);
}

extern "C" void kernel_launch(void* const* d_in, const int* in_sizes, int n_in,
                              void* d_out, int out_size, void* d_ws, size_t ws_size,
                              hipStream_t stream) {
  const float* x = (const float*)d_in[0];
  const float* y = (const float*)d_in[1];
  float* out = (float*)d_out;

  const size_t xb_off  = 0;
  const size_t yb_off  = (size_t)NB * T1 * DHEAD * sizeof(ushort);           // 2 MB
  const size_t W_off   = 2 * yb_off;                                          // 4 MB
  const size_t res_off = W_off + (size_t)3 * NB * T1 * T1 * sizeof(__half);   // +50.33 MB
  const size_t need    = res_off + NP * sizeof(float);

  if (ws_size < need) {
    hipMemsetAsync(d_out, 0xFF, (size_t)out_size * sizeof(float), stream);
    return;
  }

  ushort* xb  = (ushort*)((char*)d_ws + xb_off);
  ushort* yb  = (ushort*)((char*)d_ws + yb_off);
  __half* W   = (__half*)((char*)d_ws + W_off);
  float*  res = (float*)((char*)d_ws + res_off);

  hipLaunchKernelGGL(k_normalize, dim3(8192), dim3(256), 0, stream, x, y, xb, yb);
  hipLaunchKernelGGL(k_gemm_w, dim3(4, 4, 96), dim3(256), 0, stream, xb, yb, W);
  hipLaunchKernelGGL(k_dtw, dim3(NP), dim3(64), 0, stream, W, res);
  hipLaunchKernelGGL(k_combine, dim3(1), dim3(64), 0, stream, res, out);
}

// Round 8
// 119.460 us; speedup vs baseline: 1.2167x; 1.2167x over previous
//
#include <hip/hip_runtime.h>
#include <hip/hip_fp16.h>

#define T1 512
#define NB 32      // batches
#define NP 96      // 3 pairs * 32 batches
#define DHEAD 64

#define RSLOTS 128                 // LDS ring slots (1 KB column each) = 131072 B, pow2
#define RBYTES (RSLOTS * 1024)
#define PFD 20                     // producer prefetch distance (columns ahead)

typedef __attribute__((ext_vector_type(8))) short bf16x8;
typedef __attribute__((ext_vector_type(4))) float f32x4;
typedef __attribute__((ext_vector_type(4))) unsigned int u32x4;

// ---------------- kernel 1: row-normalize x,y -> bf16 ----------------
__global__ __launch_bounds__(256) void k_normalize(const float* __restrict__ x,
                                                   const float* __restrict__ y,
                                                   ushort* __restrict__ xb,
                                                   ushort* __restrict__ yb) {
  int wid  = threadIdx.x >> 6;
  int lane = threadIdx.x & 63;
  int row  = blockIdx.x * 4 + wid;          // 0 .. 32767
  const float* src; ushort* dst;
  if (row < NB * T1) { src = x + (size_t)row * DHEAD;            dst = xb + (size_t)row * DHEAD; }
  else { int r2 = row - NB * T1; src = y + (size_t)r2 * DHEAD;   dst = yb + (size_t)r2 * DHEAD; }
  float v = src[lane];
  float s = v * v;
  #pragma unroll
  for (int off = 32; off > 0; off >>= 1) s += __shfl_xor(s, off);
  float rn = 1.0f / fmaxf(sqrtf(s), 1e-12f);
  float o = v * rn;
  unsigned u = __float_as_uint(o);
  unsigned r = (u + 0x7fffu + ((u >> 16) & 1u)) >> 16;   // RNE to bf16
  dst[lane] = (ushort)r;
}

// ---------------- kernel 2: MFMA bf16 GEMM -> W[p][b][j][i] = exp(-(1-dot)) f16 ----------------
// 256 thr = 4 waves (2x2), tile 128x128, wave tile 64x64. K=64 = 2 mfma k-steps.
// Fragments loaded directly from global (xb/yb K-contiguous, L2-resident).
__global__ __launch_bounds__(256) void k_gemm_w(const ushort* __restrict__ xb,
                                                const ushort* __restrict__ yb,
                                                __half* __restrict__ W) {
  int pb = blockIdx.z;            // 0..95
  int p  = pb >> 5;               // 0:xy 1:xx 2:yy
  int b  = pb & 31;
  const ushort* A  = ((p == 2) ? yb : xb) + (size_t)b * T1 * DHEAD;  // i-side (M)
  const ushort* Bm = ((p == 1) ? xb : yb) + (size_t)b * T1 * DHEAD;  // j-side (N)

  int wid = threadIdx.x >> 6, lane = threadIdx.x & 63;
  int wm = wid >> 1, wn = wid & 1;
  int i0 = blockIdx.x * 128 + wm * 64;
  int j0 = blockIdx.y * 128 + wn * 64;
  int lr = lane & 15, kg = lane >> 4;

  f32x4 acc[4][4];
  #pragma unroll
  for (int ic = 0; ic < 4; ++ic)
    #pragma unroll
    for (int jc = 0; jc < 4; ++jc) acc[ic][jc] = (f32x4){0.f, 0.f, 0.f, 0.f};

  #pragma unroll
  for (int kk = 0; kk < 2; ++kk) {
    int ko = kk * 32 + kg * 8;
    bf16x8 af[4], bf[4];
    #pragma unroll
    for (int ic = 0; ic < 4; ++ic)
      af[ic] = *reinterpret_cast<const bf16x8*>(A + (size_t)(i0 + ic * 16 + lr) * DHEAD + ko);
    #pragma unroll
    for (int jc = 0; jc < 4; ++jc)
      bf[jc] = *reinterpret_cast<const bf16x8*>(Bm + (size_t)(j0 + jc * 16 + lr) * DHEAD + ko);
    #pragma unroll
    for (int ic = 0; ic < 4; ++ic)
      #pragma unroll
      for (int jc = 0; jc < 4; ++jc)
        acc[ic][jc] = __builtin_amdgcn_mfma_f32_16x16x32_bf16(af[ic], bf[jc], acc[ic][jc], 0, 0, 0);
  }

  // epilogue: D col = lane&15 -> j, row = (lane>>4)*4 + r -> i; pack 4 i's as 8B store
  const float NLOG2E = -1.44269504088896340736f;
  __half* Wp = W + (size_t)pb * (T1 * T1);
  int ib = kg << 2;
  #pragma unroll
  for (int ic = 0; ic < 4; ++ic) {
    int i = i0 + ic * 16 + ib;
    #pragma unroll
    for (int jc = 0; jc < 4; ++jc) {
      int j = j0 + jc * 16 + lr;
      union { __half h[4]; uint2 u; } pk;
      #pragma unroll
      for (int r = 0; r < 4; ++r) {
        float d = 1.0f - acc[ic][jc][r];
        pk.h[r] = __float2half(exp2f(NLOG2E * d));
      }
      *reinterpret_cast<uint2*>(Wp + (size_t)j * T1 + i) = pk.u;
    }
  }
}

// ---------------- kernel 3: soft-DTW, exp domain, skew-1, DPP exchange, LDS ring ---------
// Lane l owns DP rows 8l+1..8l+8; processes W col j = t - l at step t (575 active steps).
// Lane exchange via DPP wave_shr:1 (pure VALU, NO lgkmcnt) — removes the per-step
// ds_bpermute + lgkmcnt(0) drain that serialized rounds 2-7 at 260-410 cyc/step.
//   up(t)   = neighbor V[7] end of t-1 = DPP of live V[7] (lockstep wave).
//   diag(t) = neighbor V[7] end of t-2 = DPP of pv7 (captured at prev step top).
// Each value pairs with the base captured at the same time; ldexp converts exactly.
// W feed: 128-slot (pow2) LDS column ring, global_load_lds_dwordx4 producer PFD=20
// ahead, ONE counted vmcnt(10) per 8-step group; consumer ds_read_b128 2 steps ahead.
// Margins: group top needs cols <= tb+9 = issued(tb+20) - 10 landed ✓; WAR: col c+128
// written at step c+108 > last read of col c at step c+61 ✓.
__global__ __launch_bounds__(64, 1) void k_dtw(const __half* __restrict__ W,
                                               float* __restrict__ res) {
  __shared__ __attribute__((aligned(16))) char ring[RBYTES];
  int prob = blockIdx.x;
  const __half* Wp = W + (size_t)prob * (T1 * T1);
  int lane = threadIdx.x;

  float V[8];
  #pragma unroll
  for (int r = 0; r < 8; ++r) V[r] = 0.f;
  float B2 = 0.f;                          // base, log2 units (integer-valued, exact)
  float pv7 = 0.f, pvB = 0.f;              // V[7]/B2 captured at previous step top

  auto dppshr = [](float v) -> float {     // lane l <- lane l-1, lane 0 <- 0 (VALU only)
    return __int_as_float(__builtin_amdgcn_update_dpp(
        0, __float_as_int(v), 0x138 /*wave_shr:1*/, 0xF, 0xF, true));
  };

  // producer: DMA column c into its ring slot (uniform slot base; per-lane global addr)
  auto issueLoad = [&](int c) {
    int cc = c > T1 - 1 ? T1 - 1 : c;                 // clamp keeps vmcnt cadence uniform
    const __half* gp = Wp + ((size_t)cc << 9) + (lane << 3);
    char* lp = &ring[(cc & (RSLOTS - 1)) << 10];      // wave-uniform (cc uniform)
    __builtin_amdgcn_global_load_lds(
        (const __attribute__((address_space(1))) void*)gp,
        (__attribute__((address_space(3))) void*)lp, 16, 0, 0);
  };

  // consumer: my 16B slice of the column for step t (col j = clamp(t - lane))
  auto readSlot = [&](int t) -> u32x4 {
    int j = t - lane;
    j = j < 0 ? 0 : (j > T1 - 1 ? T1 - 1 : j);
    return *reinterpret_cast<const u32x4*>(
        &ring[((j & (RSLOTS - 1)) << 10) + (lane << 4)]);
  };

  auto step = [&](int t, u32x4 raw, bool renorm) {
    float nbUp  = dppshr(V[7]);        // neighbor col j   (end of t-1)
    float nbUpB = dppshr(B2);
    float nbDg  = dppshr(pv7);         // neighbor col j-1 (end of t-2)
    float nbDgB = dppshr(pvB);
    pv7 = V[7]; pvB = B2;              // capture for next step
    if (lane == 0) {                   // DP row 0 boundary: E=0 except E[0][0]=1
      nbUp = 0.f; nbUpB = B2;
      nbDg = (t == 0) ? 1.f : 0.f; nbDgB = B2;
    }
    int du = (int)(B2 - nbUpB); du = du > 160 ? 160 : (du < -160 ? -160 : du);
    int dd = (int)(B2 - nbDgB); dd = dd > 160 ? 160 : (dd < -160 ? -160 : dd);
    float up = ldexpf(nbUp, du);       // exact base conversion (power of 2)
    float dg = ldexpf(nbDg, dd);

    union { u32x4 u; __half h[8]; } cv; cv.u = raw;
    float wv[8];
    #pragma unroll
    for (int r = 0; r < 8; ++r) wv[r] = __half2float(cv.h[r]);

    int j = t - lane;
    bool active = ((unsigned)j < (unsigned)T1);
    if (active) {
      float c = fmaf(wv[0], up, wv[0] * (dg + V[0]));
      float Vn[8]; Vn[0] = c;
      #pragma unroll
      for (int r = 1; r < 8; ++r) {
        c = fmaf(wv[r], c, wv[r] * (V[r-1] + V[r]));
        Vn[r] = c;
      }
      if (renorm) {
        float m = fmaxf(fmaxf(fmaxf(Vn[0], Vn[1]), fmaxf(Vn[2], Vn[3])),
                        fmaxf(fmaxf(Vn[4], Vn[5]), fmaxf(Vn[6], Vn[7])));
        int e = (int)((__float_as_uint(m) >> 23) & 0xFF) - 127;
        e = e < -126 ? -126 : (e > 126 ? 126 : e);
        float sc = __uint_as_float((unsigned)(127 - e) << 23);  // 2^(-e), exact
        #pragma unroll
        for (int r = 0; r < 8; ++r) V[r] = Vn[r] * sc;
        B2 -= (float)e;
      } else {
        #pragma unroll
        for (int r = 0; r < 8; ++r) V[r] = Vn[r];
      }
    }
  };

  // producer prologue: columns 0..19 in flight; cols 0,1 landed after vmcnt(18)
  #pragma unroll
  for (int c = 0; c < PFD; ++c) issueLoad(c);
  asm volatile("s_waitcnt vmcnt(18)" ::: "memory");
  u32x4 d0 = readSlot(0);
  u32x4 d1 = readSlot(1);

  for (int tb = 0; tb < 576; tb += 8) {     // lane63 last active col at t=574
    asm volatile("s_waitcnt vmcnt(10)" ::: "memory");  // cols <= tb+9 landed
    #pragma unroll
    for (int k = 0; k < 8; ++k) {
      u32x4 d2 = readSlot(tb + k + 2);      // LDS read 2 steps ahead
      step(tb + k, d0, (k == 7));
      issueLoad(tb + k + PFD);              // keep 20 columns in flight
      d0 = d1; d1 = d2;
    }
  }

  if (lane == 63) {
    res[prob] = (B2 - log2f(V[7])) * 0.69314718055994530942f;
  }
}

// ---------------- kernel 4: combine ----------------
__global__ void k_combine(const float* __restrict__ res, float* __restrict__ out) {
  int b = threadIdx.x;
  if (b < NB) out[b] = res[b] - 0.5f * (res[NB + b] + res[2 * NB + b]);
}

extern "C" void kernel_launch(void* const* d_in, const int* in_sizes, int n_in,
                              void* d_out, int out_size, void* d_ws, size_t ws_size,
                              hipStream_t stream) {
  const float* x = (const float*)d_in[0];
  const float* y = (const float*)d_in[1];
  float* out = (float*)d_out;

  const size_t xb_off  = 0;
  const size_t yb_off  = (size_t)NB * T1 * DHEAD * sizeof(ushort);           // 2 MB
  const size_t W_off   = 2 * yb_off;                                          // 4 MB
  const size_t res_off = W_off + (size_t)3 * NB * T1 * T1 * sizeof(__half);   // +50.33 MB
  const size_t need    = res_off + NP * sizeof(float);

  if (ws_size < need) {
    hipMemsetAsync(d_out, 0xFF, (size_t)out_size * sizeof(float), stream);
    return;
  }

  ushort* xb  = (ushort*)((char*)d_ws + xb_off);
  ushort* yb  = (ushort*)((char*)d_ws + yb_off);
  __half* W   = (__half*)((char*)d_ws + W_off);
  float*  res = (float*)((char*)d_ws + res_off);

  hipLaunchKernelGGL(k_normalize, dim3(8192), dim3(256), 0, stream, x, y, xb, yb);
  hipLaunchKernelGGL(k_gemm_w, dim3(4, 4, 96), dim3(256), 0, stream, xb, yb, W);
  hipLaunchKernelGGL(k_dtw, dim3(NP), dim3(64), 0, stream, W, res);
  hipLaunchKernelGGL(k_combine, dim3(1), dim3(64), 0, stream, res, out);
}

// Round 9
// 101.650 us; speedup vs baseline: 1.4299x; 1.1752x over previous
//
#include <hip/hip_runtime.h>
#include <hip/hip_fp16.h>

#define T1 512
#define NB 32      // batches
#define NP 96      // 3 pairs * 32 batches
#define DHEAD 64

#define RSLOTS 128                 // LDS ring slots (1 KB column each) = 131072 B, pow2
#define RBYTES (RSLOTS * 1024)
#define PFD 24                     // producer prefetch distance (columns ahead)

typedef __attribute__((ext_vector_type(8))) short bf16x8;
typedef __attribute__((ext_vector_type(4))) float f32x4;
typedef __attribute__((ext_vector_type(4))) unsigned int u32x4;

// ---------------- kernel 1: row-normalize x,y -> bf16 ----------------
__global__ __launch_bounds__(256) void k_normalize(const float* __restrict__ x,
                                                   const float* __restrict__ y,
                                                   ushort* __restrict__ xb,
                                                   ushort* __restrict__ yb) {
  int wid  = threadIdx.x >> 6;
  int lane = threadIdx.x & 63;
  int row  = blockIdx.x * 4 + wid;          // 0 .. 32767
  const float* src; ushort* dst;
  if (row < NB * T1) { src = x + (size_t)row * DHEAD;            dst = xb + (size_t)row * DHEAD; }
  else { int r2 = row - NB * T1; src = y + (size_t)r2 * DHEAD;   dst = yb + (size_t)r2 * DHEAD; }
  float v = src[lane];
  float s = v * v;
  #pragma unroll
  for (int off = 32; off > 0; off >>= 1) s += __shfl_xor(s, off);
  float rn = 1.0f / fmaxf(sqrtf(s), 1e-12f);
  float o = v * rn;
  unsigned u = __float_as_uint(o);
  unsigned r = (u + 0x7fffu + ((u >> 16) & 1u)) >> 16;   // RNE to bf16
  dst[lane] = (ushort)r;
}

// ---------------- kernel 2: MFMA bf16 GEMM -> W[p][b][j][i] = exp(-(1-dot)) f16 ----------------
__global__ __launch_bounds__(256) void k_gemm_w(const ushort* __restrict__ xb,
                                                const ushort* __restrict__ yb,
                                                __half* __restrict__ W) {
  int pb = blockIdx.z;            // 0..95
  int p  = pb >> 5;               // 0:xy 1:xx 2:yy
  int b  = pb & 31;
  const ushort* A  = ((p == 2) ? yb : xb) + (size_t)b * T1 * DHEAD;  // i-side (M)
  const ushort* Bm = ((p == 1) ? xb : yb) + (size_t)b * T1 * DHEAD;  // j-side (N)

  int wid = threadIdx.x >> 6, lane = threadIdx.x & 63;
  int wm = wid >> 1, wn = wid & 1;
  int i0 = blockIdx.x * 128 + wm * 64;
  int j0 = blockIdx.y * 128 + wn * 64;
  int lr = lane & 15, kg = lane >> 4;

  f32x4 acc[4][4];
  #pragma unroll
  for (int ic = 0; ic < 4; ++ic)
    #pragma unroll
    for (int jc = 0; jc < 4; ++jc) acc[ic][jc] = (f32x4){0.f, 0.f, 0.f, 0.f};

  #pragma unroll
  for (int kk = 0; kk < 2; ++kk) {
    int ko = kk * 32 + kg * 8;
    bf16x8 af[4], bf[4];
    #pragma unroll
    for (int ic = 0; ic < 4; ++ic)
      af[ic] = *reinterpret_cast<const bf16x8*>(A + (size_t)(i0 + ic * 16 + lr) * DHEAD + ko);
    #pragma unroll
    for (int jc = 0; jc < 4; ++jc)
      bf[jc] = *reinterpret_cast<const bf16x8*>(Bm + (size_t)(j0 + jc * 16 + lr) * DHEAD + ko);
    #pragma unroll
    for (int ic = 0; ic < 4; ++ic)
      #pragma unroll
      for (int jc = 0; jc < 4; ++jc)
        acc[ic][jc] = __builtin_amdgcn_mfma_f32_16x16x32_bf16(af[ic], bf[jc], acc[ic][jc], 0, 0, 0);
  }

  const float NLOG2E = -1.44269504088896340736f;
  __half* Wp = W + (size_t)pb * (T1 * T1);
  int ib = kg << 2;
  #pragma unroll
  for (int ic = 0; ic < 4; ++ic) {
    int i = i0 + ic * 16 + ib;
    #pragma unroll
    for (int jc = 0; jc < 4; ++jc) {
      int j = j0 + jc * 16 + lr;
      union { __half h[4]; uint2 u; } pk;
      #pragma unroll
      for (int r = 0; r < 4; ++r) {
        float d = 1.0f - acc[ic][jc][r];
        pk.h[r] = __float2half(exp2f(NLOG2E * d));
      }
      *reinterpret_cast<uint2*>(Wp + (size_t)j * T1 + i) = pk.u;
    }
  }
}

// ---------------- kernel 3: soft-DTW, exp domain, skew-1, instruction-minimized ----------
// Lane l owns DP rows 8l+1..8l+8; col j = t - l at step t (576 steps, 72 groups of 8).
// Per step: 2 DPP (bound_ctrl zero-fills lane 0) + 2 base-convert muls + 17-op FMA chain
// + 8 cvt + addr/issue. Base scales hoisted per group (renorm cadence is wave-uniform,
// so adjacent-lane base diffs are group-constant; k=0's diag uses the pre-renorm
// neighbor base via B2p). Ping-pong Va/Vb kills V=Vn copies; the "end of t-2" diag
// source is exactly the array being overwritten. Seed E[0][0]=1 enters via peeled group 0.
// W feed: 128-slot LDS ring, 1 column DMA per step PFD=24 ahead, ONE counted vmcnt(13)
// per group (guarantees cols <= tb+10 landed: covers the 3-ahead ds_reads; col tb+10
// was issued ~14 steps earlier). WAR: slot reuse col c vs c+128 issued at step c+104 >
// last LDS read of col c at step c+60. Clamped producer cols re-DMA col 511 (idempotent).
__global__ __launch_bounds__(64, 1) void k_dtw(const __half* __restrict__ W,
                                               float* __restrict__ res) {
  __shared__ __attribute__((aligned(16))) char ring[RBYTES];
  const int prob = blockIdx.x;
  const __half* Wp = W + (size_t)prob * (T1 * T1);
  const int lane = threadIdx.x;

  float Va[8], Vb[8];
  #pragma unroll
  for (int r = 0; r < 8; ++r) { Va[r] = 0.f; Vb[r] = 0.f; }
  float B2 = 0.f, B2p = 0.f;             // base (log2 units, int-valued) and pre-renorm base
  const float dgSeed = (lane == 0) ? 1.0f : 0.0f;

  auto dppshr = [](float v) -> float {   // lane l <- lane l-1; lane 0 <- 0 (VALU only)
    return __int_as_float(__builtin_amdgcn_update_dpp(
        0, __float_as_int(v), 0x138 /*wave_shr:1*/, 0xF, 0xF, true));
  };

  auto issueLoad = [&](int c) {
    int cc = c > T1 - 1 ? T1 - 1 : c;
    const __half* gp = Wp + ((size_t)cc << 9) + (lane << 3);
    char* lp = &ring[(cc & (RSLOTS - 1)) << 10];
    __builtin_amdgcn_global_load_lds(
        (const __attribute__((address_space(1))) void*)gp,
        (__attribute__((address_space(3))) void*)lp, 16, 0, 0);
  };

  auto readSlot = [&](int t) -> u32x4 {  // data slice for step t; no clamp: garbage slots
    int j = t - lane;                    // only feed lanes that are inactive at consume
    return *reinterpret_cast<const u32x4*>(
        &ring[((j & (RSLOTS - 1)) << 10) + (lane << 4)]);
  };

#define DTW_STEP(kk, VIN, VOUT, SDG, INJSEED) do {                            \
    const int t_ = tb + (kk);                                                 \
    float nbUp_ = dppshr(VIN[7]);            /* neighbor end of t-1 */        \
    float nbDg_ = dppshr(VOUT[7]);           /* neighbor end of t-2 */        \
    float up_ = nbUp_ * sUp;                                                  \
    float dg_ = nbDg_ * (SDG);                                                \
    if (INJSEED) dg_ = dgSeed;               /* t=0 only: all nbDg_=0 */      \
    union { u32x4 u; __half h[8]; } cv_; cv_.u = d0;                          \
    float wv_[8];                                                             \
    _Pragma("unroll")                                                         \
    for (int r = 0; r < 8; ++r) wv_[r] = __half2float(cv_.h[r]);              \
    d0 = d1; d1 = d2; d2 = readSlot(t_ + 3);                                  \
    issueLoad(t_ + PFD);                                                      \
    int j_ = t_ - lane;                                                       \
    if ((unsigned)j_ < (unsigned)T1) {                                        \
      float c_ = fmaf(wv_[0], up_, wv_[0] * (dg_ + VIN[0]));                  \
      VOUT[0] = c_;                                                           \
      _Pragma("unroll")                                                       \
      for (int r = 1; r < 8; ++r) {                                           \
        c_ = fmaf(wv_[r], c_, wv_[r] * (VIN[r-1] + VIN[r]));                  \
        VOUT[r] = c_;                                                         \
      }                                                                       \
      if ((kk) == 7) {                       /* exact pow2 renorm, per group */ \
        float m_ = fmaxf(fmaxf(fmaxf(VOUT[0],VOUT[1]),fmaxf(VOUT[2],VOUT[3])),\
                         fmaxf(fmaxf(VOUT[4],VOUT[5]),fmaxf(VOUT[6],VOUT[7])));\
        int e_ = (int)((__float_as_uint(m_) >> 23) & 0xFF) - 127;             \
        e_ = e_ < -126 ? -126 : (e_ > 126 ? 126 : e_);                        \
        float sc_ = __uint_as_float((unsigned)(127 - e_) << 23);              \
        _Pragma("unroll")                                                     \
        for (int r = 0; r < 8; ++r) VOUT[r] *= sc_;                           \
        B2p = B2; B2 -= (float)e_;                                            \
      }                                                                       \
    }                                                                         \
  } while (0)

#define DTW_GROUP(SEEDFLAG) do {                                              \
    asm volatile("s_waitcnt vmcnt(13)" ::: "memory");  /* cols <= tb+10 in */ \
    float nbBn_ = dppshr(B2);                /* neighbor base, post-renorm */ \
    float nbBo_ = dppshr(B2p);               /* neighbor base, pre-renorm  */ \
    int du_ = (int)fminf(fmaxf(B2 - nbBn_, -120.f), 120.f);                   \
    int dd_ = (int)fminf(fmaxf(B2 - nbBo_, -120.f), 120.f);                   \
    float sUp  = __uint_as_float((unsigned)(127 + du_) << 23);  /* 2^du */    \
    float sDg0 = __uint_as_float((unsigned)(127 + dd_) << 23);  /* 2^dd */    \
    DTW_STEP(0, Va, Vb, sDg0, SEEDFLAG);                                      \
    DTW_STEP(1, Vb, Va, sUp, false);                                          \
    DTW_STEP(2, Va, Vb, sUp, false);                                          \
    DTW_STEP(3, Vb, Va, sUp, false);                                          \
    DTW_STEP(4, Va, Vb, sUp, false);                                          \
    DTW_STEP(5, Vb, Va, sUp, false);                                          \
    DTW_STEP(6, Va, Vb, sUp, false);                                          \
    DTW_STEP(7, Vb, Va, sUp, false);                                          \
  } while (0)

  // prologue: 24 columns in flight; cols 0..2 landed for the 3-deep read pipe
  #pragma unroll
  for (int c = 0; c < PFD; ++c) issueLoad(c);
  asm volatile("s_waitcnt vmcnt(21)" ::: "memory");
  u32x4 d0 = readSlot(0), d1 = readSlot(1), d2 = readSlot(2);

  { const int tb = 0; DTW_GROUP(true); }     // peeled: carries the E[0][0]=1 seed
  for (int tb = 8; tb < 576; tb += 8) DTW_GROUP(false);

  if (lane == 63) {
    // final state in Va (last step t=575 wrote Va); R[512][512] = (B2 - log2 Va[7]) ln2
    res[prob] = (B2 - log2f(Va[7])) * 0.69314718055994530942f;
  }
#undef DTW_STEP
#undef DTW_GROUP
}

// ---------------- kernel 4: combine ----------------
__global__ void k_combine(const float* __restrict__ res, float* __restrict__ out) {
  int b = threadIdx.x;
  if (b < NB) out[b] = res[b] - 0.5f * (res[NB + b] + res[2 * NB + b]);
}

extern "C" void kernel_launch(void* const* d_in, const int* in_sizes, int n_in,
                              void* d_out, int out_size, void* d_ws, size_t ws_size,
                              hipStream_t stream) {
  const float* x = (const float*)d_in[0];
  const float* y = (const float*)d_in[1];
  float* out = (float*)d_out;

  const size_t xb_off  = 0;
  const size_t yb_off  = (size_t)NB * T1 * DHEAD * sizeof(ushort);           // 2 MB
  const size_t W_off   = 2 * yb_off;                                          // 4 MB
  const size_t res_off = W_off + (size_t)3 * NB * T1 * T1 * sizeof(__half);   // +50.33 MB
  const size_t need    = res_off + NP * sizeof(float);

  if (ws_size < need) {
    hipMemsetAsync(d_out, 0xFF, (size_t)out_size * sizeof(float), stream);
    return;
  }

  ushort* xb  = (ushort*)((char*)d_ws + xb_off);
  ushort* yb  = (ushort*)((char*)d_ws + yb_off);
  __half* W   = (__half*)((char*)d_ws + W_off);
  float*  res = (float*)((char*)d_ws + res_off);

  hipLaunchKernelGGL(k_normalize, dim3(8192), dim3(256), 0, stream, x, y, xb, yb);
  hipLaunchKernelGGL(k_gemm_w, dim3(4, 4, 96), dim3(256), 0, stream, xb, yb, W);
  hipLaunchKernelGGL(k_dtw, dim3(NP), dim3(64), 0, stream, W, res);
  hipLaunchKernelGGL(k_combine, dim3(1), dim3(64), 0, stream, res, out);
}

// Round 10
// 92.182 us; speedup vs baseline: 1.5768x; 1.1027x over previous
//
#include <hip/hip_runtime.h>
#include <hip/hip_fp16.h>

#define T1 512
#define NB 32      // batches
#define NP 96      // 3 pairs * 32 batches
#define DHEAD 64

#define RSLOTS 128                 // LDS ring slots (1 KB column each) = 131072 B, pow2
#define RBYTES (RSLOTS * 1024)
#define PFD 32                     // producer prefetch distance (columns ahead)

typedef __attribute__((ext_vector_type(8))) short bf16x8;
typedef __attribute__((ext_vector_type(4))) float f32x4;
typedef __attribute__((ext_vector_type(4))) unsigned int u32x4;

// ---------------- kernel 1: row-normalize x,y -> bf16 ----------------
__global__ __launch_bounds__(256) void k_normalize(const float* __restrict__ x,
                                                   const float* __restrict__ y,
                                                   ushort* __restrict__ xb,
                                                   ushort* __restrict__ yb) {
  int wid  = threadIdx.x >> 6;
  int lane = threadIdx.x & 63;
  int row  = blockIdx.x * 4 + wid;          // 0 .. 32767
  const float* src; ushort* dst;
  if (row < NB * T1) { src = x + (size_t)row * DHEAD;            dst = xb + (size_t)row * DHEAD; }
  else { int r2 = row - NB * T1; src = y + (size_t)r2 * DHEAD;   dst = yb + (size_t)r2 * DHEAD; }
  float v = src[lane];
  float s = v * v;
  #pragma unroll
  for (int off = 32; off > 0; off >>= 1) s += __shfl_xor(s, off);
  float rn = 1.0f / fmaxf(sqrtf(s), 1e-12f);
  float o = v * rn;
  unsigned u = __float_as_uint(o);
  unsigned r = (u + 0x7fffu + ((u >> 16) & 1u)) >> 16;   // RNE to bf16
  dst[lane] = (ushort)r;
}

// ---------------- kernel 2: MFMA bf16 GEMM -> W[p][b][j][i] = exp(-(1-dot)) f16 ----------------
__global__ __launch_bounds__(256) void k_gemm_w(const ushort* __restrict__ xb,
                                                const ushort* __restrict__ yb,
                                                __half* __restrict__ W) {
  int pb = blockIdx.z;            // 0..95
  int p  = pb >> 5;               // 0:xy 1:xx 2:yy
  int b  = pb & 31;
  const ushort* A  = ((p == 2) ? yb : xb) + (size_t)b * T1 * DHEAD;  // i-side (M)
  const ushort* Bm = ((p == 1) ? xb : yb) + (size_t)b * T1 * DHEAD;  // j-side (N)

  int wid = threadIdx.x >> 6, lane = threadIdx.x & 63;
  int wm = wid >> 1, wn = wid & 1;
  int i0 = blockIdx.x * 128 + wm * 64;
  int j0 = blockIdx.y * 128 + wn * 64;
  int lr = lane & 15, kg = lane >> 4;

  f32x4 acc[4][4];
  #pragma unroll
  for (int ic = 0; ic < 4; ++ic)
    #pragma unroll
    for (int jc = 0; jc < 4; ++jc) acc[ic][jc] = (f32x4){0.f, 0.f, 0.f, 0.f};

  #pragma unroll
  for (int kk = 0; kk < 2; ++kk) {
    int ko = kk * 32 + kg * 8;
    bf16x8 af[4], bf[4];
    #pragma unroll
    for (int ic = 0; ic < 4; ++ic)
      af[ic] = *reinterpret_cast<const bf16x8*>(A + (size_t)(i0 + ic * 16 + lr) * DHEAD + ko);
    #pragma unroll
    for (int jc = 0; jc < 4; ++jc)
      bf[jc] = *reinterpret_cast<const bf16x8*>(Bm + (size_t)(j0 + jc * 16 + lr) * DHEAD + ko);
    #pragma unroll
    for (int ic = 0; ic < 4; ++ic)
      #pragma unroll
      for (int jc = 0; jc < 4; ++jc)
        acc[ic][jc] = __builtin_amdgcn_mfma_f32_16x16x32_bf16(af[ic], bf[jc], acc[ic][jc], 0, 0, 0);
  }

  const float NLOG2E = -1.44269504088896340736f;
  __half* Wp = W + (size_t)pb * (T1 * T1);
  int ib = kg << 2;
  #pragma unroll
  for (int ic = 0; ic < 4; ++ic) {
    int i = i0 + ic * 16 + ib;
    #pragma unroll
    for (int jc = 0; jc < 4; ++jc) {
      int j = j0 + jc * 16 + lr;
      union { __half h[4]; uint2 u; } pk;
      #pragma unroll
      for (int r = 0; r < 4; ++r) {
        float d = 1.0f - acc[ic][jc][r];
        pk.h[r] = __float2half(exp2f(NLOG2E * d));
      }
      *reinterpret_cast<uint2*>(Wp + (size_t)j * T1 + i) = pk.u;
    }
  }
}

// ---------------- kernel 3: soft-DTW, exp domain, skew-1, minimal bookkeeping ----------
// DP math identical to rounds 4-9 (exact pow2 renorm every 8 steps, group-hoisted base
// scales, DPP wave_shr exchange). Bookkeeping minimized; see round-10 theory notes.
// Guard policy: groups with t<64 guarded (pre-active lanes may consume never-written
// LDS junk -> must not update state); last group guarded (protects lane63 at t=575);
// middle 63 groups unguarded (post-active garbage never reaches an active consumer).
__global__ __launch_bounds__(64, 1) void k_dtw(const __half* __restrict__ W,
                                               float* __restrict__ res) {
  __shared__ __attribute__((aligned(16))) char ring[RBYTES];
  const int prob = blockIdx.x;
  const __half* Wp = W + (size_t)prob * (T1 * T1);
  const int lane = threadIdx.x;

  float Va[8], Vb[8];
  #pragma unroll
  for (int r = 0; r < 8; ++r) { Va[r] = 0.f; Vb[r] = 0.f; }
  float B2 = 0.f, B2p = 0.f;
  const float dgSeed = (lane == 0) ? 1.0f : 0.0f;

  auto dppshr = [](float v) -> float {   // lane l <- lane l-1; lane 0 <- 0 (VALU only)
    return __int_as_float(__builtin_amdgcn_update_dpp(
        0, __float_as_int(v), 0x138 /*wave_shr:1*/, 0xF, 0xF, true));
  };

  // producer state: per-lane global src ptr (col 32 onward) + uniform LDS slot offset
  const char* gsrc = (const char*)Wp + (size_t)PFD * 1024 + (lane << 4);
  unsigned lslot = (PFD << 10) & (RBYTES - 1);

  // prologue: issue cols 0..31
  #pragma unroll
  for (int c = 0; c < PFD; ++c) {
    const __half* gp = Wp + ((size_t)c << 9) + (lane << 3);
    __builtin_amdgcn_global_load_lds(
        (const __attribute__((address_space(1))) void*)gp,
        (__attribute__((address_space(3))) void*)(ring + ((unsigned)(c << 10))), 16, 0, 0);
  }
  asm volatile("s_waitcnt vmcnt(24)" ::: "memory");   // cols 0..7 landed

  u32x4 d0, d1, d2, d3, d4, d5, d6, d7;
  unsigned va0, va1, va2, va3, va4, va5, va6, va7;
#define RS_INIT(K) do { \
    d##K = *reinterpret_cast<const u32x4*>( \
        ring + ((((unsigned)(K - lane) & 127u) << 10) | (unsigned)(lane << 4))); \
    va##K = ((((unsigned)(8 + K - lane) & 127u) << 10) | (unsigned)(lane << 4)); \
  } while (0)
  RS_INIT(0); RS_INIT(1); RS_INIT(2); RS_INIT(3);
  RS_INIT(4); RS_INIT(5); RS_INIT(6); RS_INIT(7);
#undef RS_INIT

#define DTW_STEP(KK, VIN, VOUT, SDG, SEEDK, GUARD) do {                       \
    const int t_ = tb + (KK);                                                 \
    float nbUp_ = dppshr(VIN[7]);            /* neighbor end of t-1 */        \
    float nbDg_ = dppshr(VOUT[7]);           /* neighbor end of t-2 */        \
    float up_ = nbUp_ * sUp;                                                  \
    float dg_ = nbDg_ * (SDG);                                                \
    if (SEEDK) dg_ = dgSeed;                                                  \
    union { u32x4 u; __half h[8]; } cv_; cv_.u = d##KK;                       \
    d##KK = *reinterpret_cast<const u32x4*>(ring + va##KK);  /* col t_+8 */   \
    va##KK = (va##KK + 8192u) & (RBYTES - 1);                                 \
    __builtin_amdgcn_global_load_lds(                        /* col t_+32 */  \
        (const __attribute__((address_space(1))) void*)gsrc,                  \
        (__attribute__((address_space(3))) void*)(ring + lslot), 16, 0, 0);   \
    lslot = (lslot + 1024u) & (RBYTES - 1);                                   \
    gsrc += ((t_ + PFD) < T1 - 1) ? 1024 : 0;  /* clamp at col 511 */         \
    float wv_[8];                                                             \
    _Pragma("unroll")                                                         \
    for (int r = 0; r < 8; ++r) wv_[r] = __half2float(cv_.h[r]);              \
    bool act_ = true;                                                         \
    if (GUARD) { int j_ = t_ - lane; act_ = ((unsigned)j_ < (unsigned)T1); }  \
    if (act_) {                                                               \
      float c_ = fmaf(wv_[0], up_, wv_[0] * (dg_ + VIN[0]));                  \
      VOUT[0] = c_;                                                           \
      _Pragma("unroll")                                                       \
      for (int r = 1; r < 8; ++r) {                                           \
        c_ = fmaf(wv_[r], c_, wv_[r] * (VIN[r-1] + VIN[r]));                  \
        VOUT[r] = c_;                                                         \
      }                                                                       \
      if ((KK) == 7) {                       /* exact pow2 renorm */          \
        float m_ = fmaxf(fmaxf(fmaxf(VOUT[0],VOUT[1]),fmaxf(VOUT[2],VOUT[3])),\
                         fmaxf(fmaxf(VOUT[4],VOUT[5]),fmaxf(VOUT[6],VOUT[7])));\
        int e_ = (int)((__float_as_uint(m_) >> 23) & 0xFF) - 127;             \
        e_ = e_ < -126 ? -126 : (e_ > 126 ? 126 : e_);                        \
        float sc_ = __uint_as_float((unsigned)(127 - e_) << 23);              \
        _Pragma("unroll")                                                     \
        for (int r = 0; r < 8; ++r) VOUT[r] *= sc_;                           \
        B2p = B2; B2 -= (float)e_;                                            \
      }                                                                       \
    }                                                                         \
  } while (0)

#define DTW_GROUP(GUARD, SEED) do {                                           \
    asm volatile("s_waitcnt vmcnt(16)" ::: "memory");  /* cols <= tb+15 */    \
    float nbBn_ = dppshr(B2);                /* neighbor base, post-renorm */ \
    float nbBo_ = dppshr(B2p);               /* neighbor base, pre-renorm  */ \
    float sUp  = __uint_as_float(                                             \
        (unsigned)(127 + (int)fminf(fmaxf(B2 - nbBn_, -120.f), 120.f)) << 23);\
    float sDg0 = __uint_as_float(                                             \
        (unsigned)(127 + (int)fminf(fmaxf(B2 - nbBo_, -120.f), 120.f)) << 23);\
    DTW_STEP(0, Va, Vb, sDg0, SEED, GUARD);                                   \
    DTW_STEP(1, Vb, Va, sUp, false, GUARD);                                   \
    DTW_STEP(2, Va, Vb, sUp, false, GUARD);                                   \
    DTW_STEP(3, Vb, Va, sUp, false, GUARD);                                   \
    DTW_STEP(4, Va, Vb, sUp, false, GUARD);                                   \
    DTW_STEP(5, Vb, Va, sUp, false, GUARD);                                   \
    DTW_STEP(6, Va, Vb, sUp, false, GUARD);                                   \
    DTW_STEP(7, Vb, Va, sUp, false, GUARD);                                   \
  } while (0)

  { const int tb = 0; DTW_GROUP(true, true); }          // seed group (guarded)
  #pragma unroll 1
  for (int tb = 8; tb < 64; tb += 8)  DTW_GROUP(true, false);   // pre-active era
  #pragma unroll 1
  for (int tb = 64; tb < 568; tb += 8) DTW_GROUP(false, false); // unguarded middle
  { const int tb = 568; DTW_GROUP(true, false); }       // final group (guarded)

  if (lane == 63) {
    res[prob] = (B2 - log2f(Va[7])) * 0.69314718055994530942f;
  }
#undef DTW_STEP
#undef DTW_GROUP
}

// ---------------- kernel 4: combine ----------------
__global__ void k_combine(const float* __restrict__ res, float* __restrict__ out) {
  int b = threadIdx.x;
  if (b < NB) out[b] = res[b] - 0.5f * (res[NB + b] + res[2 * NB + b]);
}

extern "C" void kernel_launch(void* const* d_in, const int* in_sizes, int n_in,
                              void* d_out, int out_size, void* d_ws, size_t ws_size,
                              hipStream_t stream) {
  const float* x = (const float*)d_in[0];
  const float* y = (const float*)d_in[1];
  float* out = (float*)d_out;

  const size_t xb_off  = 0;
  const size_t yb_off  = (size_t)NB * T1 * DHEAD * sizeof(ushort);           // 2 MB
  const size_t W_off   = 2 * yb_off;                                          // 4 MB
  const size_t res_off = W_off + (size_t)3 * NB * T1 * T1 * sizeof(__half);   // +50.33 MB
  const size_t need    = res_off + NP * sizeof(float);

  if (ws_size < need) {
    hipMemsetAsync(d_out, 0xFF, (size_t)out_size * sizeof(float), stream);
    return;
  }

  ushort* xb  = (ushort*)((char*)d_ws + xb_off);
  ushort* yb  = (ushort*)((char*)d_ws + yb_off);
  __half* W   = (__half*)((char*)d_ws + W_off);
  float*  res = (float*)((char*)d_ws + res_off);

  hipLaunchKernelGGL(k_normalize, dim3(8192), dim3(256), 0, stream, x, y, xb, yb);
  hipLaunchKernelGGL(k_gemm_w, dim3(4, 4, 96), dim3(256), 0, stream, xb, yb, W);
  hipLaunchKernelGGL(k_dtw, dim3(NP), dim3(64), 0, stream, W, res);
  hipLaunchKernelGGL(k_combine, dim3(1), dim3(64), 0, stream, res, out);
}